// Round 12
// baseline (209.551 us; speedup 1.0000x reference)
//
#include <hip/hip_runtime.h>
#include <hip/hip_bf16.h>

#define L 2048
#define HD 1024   // H*D
#define NB 8      // batch
#define NT 32     // K tiles of BK=64

using f32x4 = __attribute__((ext_vector_type(4))) float;
using fl4   = __attribute__((ext_vector_type(4))) float;
using s16x8 = __attribute__((ext_vector_type(8))) short;

__device__ __forceinline__ short f2bf(float f) {
    __hip_bfloat16 h = __float2bfloat16(f);
    short s;
    __builtin_memcpy(&s, &h, 2);
    return s;
}

__device__ __forceinline__ void gload_lds16(const void* g, void* l) {
    __builtin_amdgcn_global_load_lds(
        (const __attribute__((address_space(1))) unsigned int*)g,
        (__attribute__((address_space(3))) unsigned int*)l, 16, 0, 0);
}

// ---- prep: a_tab chunks (blocks 0..2047) ; z (block 2048) ----
// a_tab chunk index c = ((jm*32+T)*16 + wrm*2 + ki)*64 + lane, 16B each:
//   elem j (0..7): p-index p0+j, p0 = 2047 + T*64 + ki*32 + fk*8
//                                    - jm*128 - wrm*16 - fr
//   value = bf16(w[|p-2047|]) if p in [0,4094] else 0
__global__ __launch_bounds__(256) void pb_prep(const float* __restrict__ w,
                                               s16x8* __restrict__ atab,
                                               float* __restrict__ z) {
    const int t = threadIdx.x;
    if (blockIdx.x < 2048) {
        int c = blockIdx.x * 256 + t;
        int lane = c & 63;
        int f    = (c >> 6) & 15;
        int T    = (c >> 10) & 31;
        int jm   = c >> 15;
        int ki = f & 1, wrm = f >> 1;
        int fr = lane & 15, fk = lane >> 4;
        int p0 = 2047 + T * 64 + ki * 32 + fk * 8 - jm * 128 - wrm * 16 - fr;
        s16x8 val;
        #pragma unroll
        for (int j = 0; j < 8; ++j) {
            int p = p0 + j;
            int d = p - 2047; d = d < 0 ? -d : d;
            val[j] = (p >= 0 && p <= 4094) ? f2bf(w[d]) : (short)0;
        }
        atab[c] = val;
    } else {
        __shared__ float part[256];
        __shared__ float S[L];
        float loc[8]; float s = 0.f;
        #pragma unroll
        for (int i = 0; i < 8; ++i) { loc[i] = w[t * 8 + i]; s += loc[i]; }
        part[t] = s;
        __syncthreads();
        if (t == 0) {
            float a = 0.f;
            for (int i = 0; i < 256; ++i) { float tmp = part[i]; part[i] = a; a += tmp; }
        }
        __syncthreads();
        float a = part[t];
        #pragma unroll
        for (int i = 0; i < 8; ++i) { a += loc[i]; S[t * 8 + i] = a; }
        __syncthreads();
        const float w0 = S[0];
        #pragma unroll
        for (int i = 0; i < 8; ++i) {
            int j = t * 8 + i;
            z[j] = S[j] + S[2047 - j] - w0;
        }
    }
}

// ---- vt: chunk[((n*NT+kk)*1024 + c)*8 + h] (16B) =
//      bf16(v[n][kk*64 + h*8 + j][c]), j=0..7  (c = global column 0..1023) ----
__global__ __launch_bounds__(256) void pb_vtile(const float* __restrict__ v,
                                                s16x8* __restrict__ vt) {
    // Ts: (c,l) at c*64 + ((lblk ^ ((c>>2)&7))<<3) + lsub  (slot swizzle)
    __shared__ __align__(16) short Ts[256 * 64];   // 32 KB
    const int kk = blockIdx.x, cg4 = blockIdx.y, n = blockIdx.z;
    const int l0 = kk * 64, c0 = cg4 * 256;
    const int t = threadIdx.x;
    const float* vn = v + (size_t)n * L * HD;

    #pragma unroll
    for (int i = 0; i < 16; ++i) {
        int unit = i * 256 + t;          // 4096 units = 64 l x 64 quads
        int l = unit >> 6, cq = unit & 63;
        fl4 x = *(const fl4*)&vn[(size_t)(l0 + l) * HD + c0 + cq * 4];
        int lsub = l & 7, lblk = l >> 3;
        #pragma unroll
        for (int j = 0; j < 4; ++j) {
            int c = cq * 4 + j;
            Ts[c * 64 + ((lblk ^ ((c >> 2) & 7)) << 3) + lsub] = f2bf(x[j]);
        }
    }
    __syncthreads();

    s16x8* outp = vt + ((size_t)(n * NT + kk) * 1024 + c0) * 8;
    #pragma unroll
    for (int i2 = 0; i2 < 8; ++i2) {
        int ci = i2 * 256 + t;           // 2048 chunks (256 c x 8 h)
        int c = ci >> 3, h = ci & 7;
        int slot = h ^ ((c >> 2) & 7);
        outp[ci] = *(const s16x8*)&Ts[c * 64 + slot * 8];
    }
}

// ---- main GEMM: 128x128 tile, BK=64, 4 waves, 2 blocks/CU.
//      B: block-cooperative LDS dbuf (r6-validated).
//      A: lane-linear loads from a_tab, volatile-prefetched one tile
//      ahead into a register double-buffer. One __syncthreads per tile. ----
__global__ __launch_bounds__(256, 2) void pb_gemm(const s16x8* __restrict__ atab,
                                                  const short* __restrict__ vt,
                                                  float* __restrict__ out) {
    __shared__ __align__(16) short lds_[16384];  // 32 KB: 2 x 16 KB B buffers

    const int bid = blockIdx.x;
    // XCD affinity: XCD = bid%8 = cm; jm,n peers of one cm share an XCD
    const int cm = bid & 7;
    const int n  = (bid >> 3) & 7;
    const int jm = bid >> 6;
    const int j0 = jm * 128;
    const int c0 = cm * 128;

    const int t = threadIdx.x;
    const int lane = t & 63;
    const int w = t >> 6;                 // wave 0..3
    const int wr = w >> 1, wc = w & 1;    // 2x2 wave grid, 64x64 tile each
    const int fr = lane & 15, fk = lane >> 4;

    // B fragment byte-offsets within a 16 KB buffer (ki=1 via ^64)
    int offB[4];
    #pragma unroll
    for (int nf = 0; nf < 4; ++nf) {
        int c = wc * 64 + nf * 16 + fr;
        offB[nf] = c * 128 + ((fk ^ (c & 7)) << 4);
    }

    // A: lane-linear chunks from a_tab.
    // chunk = jm*32768 + T*1024 + wr*512 + (m*2+ki)*64 + lane
    const volatile s16x8* abase = (const volatile s16x8*)atab
                                  + ((size_t)jm * 32768 + wr * 512 + lane);

    // B staging sources (r6/r11-validated): chunk dc = w*256 + i*64 + lane
    const short* srcB0; const short* srcB1; const short* srcB2; const short* srcB3;
    {
        const size_t bbase = ((size_t)(n * NT) * 1024 + c0) * 8ull;
        int dc, c, h;
        dc = w * 256 + 0 * 64 + lane; c = dc >> 3; h = (dc & 7) ^ (c & 7);
        srcB0 = vt + (bbase + (size_t)c * 8 + h) * 8;
        dc = w * 256 + 1 * 64 + lane; c = dc >> 3; h = (dc & 7) ^ (c & 7);
        srcB1 = vt + (bbase + (size_t)c * 8 + h) * 8;
        dc = w * 256 + 2 * 64 + lane; c = dc >> 3; h = (dc & 7) ^ (c & 7);
        srcB2 = vt + (bbase + (size_t)c * 8 + h) * 8;
        dc = w * 256 + 3 * 64 + lane; c = dc >> 3; h = (dc & 7) ^ (c & 7);
        srcB3 = vt + (bbase + (size_t)c * 8 + h) * 8;
    }
    const int wB = w * 4096;              // wave-uniform dest base (bytes)

#define STAGE_B(par) { \
    char* _d = (char*)lds_ + (par) * 16384 + wB; \
    gload_lds16(srcB0, _d); \
    gload_lds16(srcB1, _d + 1024); \
    gload_lds16(srcB2, _d + 2048); \
    gload_lds16(srcB3, _d + 3072); \
    srcB0 += 65536; srcB1 += 65536; srcB2 += 65536; srcB3 += 65536; }

// volatile: cannot be sunk past the barrier; barrier's vmcnt(0) drain
// guarantees completion before next-body use.
#define ALOAD_V(AF, Tq) { \
    const volatile s16x8* _a = abase + (size_t)(Tq) * 1024; \
    _Pragma("unroll") \
    for (int m = 0; m < 4; ++m) \
        _Pragma("unroll") \
        for (int ki = 0; ki < 2; ++ki) \
            AF[m][ki] = _a[(m * 2 + ki) * 64]; }

#define BREAD(BF, par) { \
    const char* _b = (const char*)lds_ + (par) * 16384; \
    _Pragma("unroll") \
    for (int nf = 0; nf < 4; ++nf) { \
        BF[nf][0] = *(const s16x8*)(_b + offB[nf]); \
        BF[nf][1] = *(const s16x8*)(_b + (offB[nf] ^ 64)); } }

#define MFMA_ALL(AF, BF) { \
    __builtin_amdgcn_s_setprio(1); \
    _Pragma("unroll") \
    for (int m = 0; m < 4; ++m) \
        _Pragma("unroll") \
        for (int nf = 0; nf < 4; ++nf) \
            _Pragma("unroll") \
            for (int ki = 0; ki < 2; ++ki) \
                acc[m][nf] = __builtin_amdgcn_mfma_f32_16x16x32_bf16( \
                    AF[m][ki], BF[nf][ki], acc[m][nf], 0, 0, 0); \
    __builtin_amdgcn_s_setprio(0); }

// body T: stage B(T+1), volatile-issue A(T+1)->NXT regs, read B(T) frags,
// MFMA with CUR regs (no dependency on this body's loads), tile barrier.
#define BODY(TT, CUR, NXT, DOSTAGE) { \
    if (DOSTAGE) { STAGE_B(((TT) + 1) & 1); ALOAD_V(NXT, (TT) + 1); } \
    BREAD(bF, (TT) & 1); \
    MFMA_ALL(CUR, bF); \
    __syncthreads(); }

    f32x4 acc[4][4] = {};
    s16x8 afX[4][2], afY[4][2], bF[4][2];

    // ---- prologue: stage B(0), load A(0) ----
    STAGE_B(0);
    ALOAD_V(afX, 0);
    __syncthreads();   // drains S(0)+A(0)

    for (int T = 0; T < 30; T += 2) {
        BODY(T,     afX, afY, true);
        BODY(T + 1, afY, afX, true);
    }
    BODY(30, afX, afY, true);     // stages B(31), loads A(31)->afY
    // tile 31: no further staging
    BREAD(bF, 1);
    MFMA_ALL(afY, bF);

    // ---- epilogue: C/D layout col=lane&15, row=(lane>>4)*4+r ----
    float* outn = out + (size_t)n * L * HD;
    #pragma unroll
    for (int m = 0; m < 4; ++m) {
        const int row = j0 + wr * 64 + m * 16 + fk * 4;
        #pragma unroll
        for (int nf = 0; nf < 4; ++nf) {
            const int col = c0 + wc * 64 + nf * 16 + fr;
            #pragma unroll
            for (int r = 0; r < 4; ++r)
                outn[(size_t)(row + r) * HD + col] = acc[m][nf][r];
        }
    }
}

extern "C" void kernel_launch(void* const* d_in, const int* in_sizes, int n_in,
                              void* d_out, int out_size, void* d_ws, size_t ws_size,
                              hipStream_t stream) {
    const float* v = (const float*)d_in[0];
    const float* w = (const float*)d_in[1];
    float* out = (float*)d_out;

    s16x8* atab = (s16x8*)d_ws;                            // 8 MB
    s16x8* vt   = (s16x8*)((char*)d_ws + (8u << 20));      // 32 MB

    pb_prep<<<2049, 256, 0, stream>>>(w, atab, out + (size_t)NB * L * HD);
    pb_vtile<<<dim3(NT, 4, NB), 256, 0, stream>>>(v, vt);
    pb_gemm<<<1024, 256, 0, stream>>>(atab, (const short*)vt, out);
}

// Round 13
// 105.472 us; speedup vs baseline: 1.9868x; 1.9868x over previous
//
#include <hip/hip_runtime.h>
#include <hip/hip_bf16.h>

#define L 2048
#define HD 1024   // H*D
#define NB 8      // batch
#define NT 32     // K tiles of BK=64
#define PROW 4096 // p8 row length

using f32x4 = __attribute__((ext_vector_type(4))) float;
using fl4   = __attribute__((ext_vector_type(4))) float;
using s16x8 = __attribute__((ext_vector_type(8))) short;

__device__ __forceinline__ short f2bf(float f) {
    __hip_bfloat16 h = __float2bfloat16(f);
    short s;
    __builtin_memcpy(&s, &h, 2);
    return s;
}

__device__ __forceinline__ void gload_lds16(const void* g, void* l) {
    __builtin_amdgcn_global_load_lds(
        (const __attribute__((address_space(1))) unsigned int*)g,
        (__attribute__((address_space(3))) unsigned int*)l, 16, 0, 0);
}

// ---- fused: p8[s][x] = bf16(p[x+s]) (blocks 0..127) ; z (block 128) ----
__global__ __launch_bounds__(256) void pb_prep(const float* __restrict__ w,
                                               short* __restrict__ p8,
                                               float* __restrict__ z) {
    __shared__ float part[256];
    __shared__ float S[L];
    const int t = threadIdx.x;
    if (blockIdx.x < 128) {
        int idx = blockIdx.x * 256 + t;
        int s = idx >> 12;
        int x = idx & (PROW - 1);
        int k = x + s;
        short val = 0;
        if (k <= 4094) {
            int d = k - 2047; d = d < 0 ? -d : d;
            val = f2bf(w[d]);
        }
        p8[idx] = val;
    } else {
        float loc[8]; float s = 0.f;
        #pragma unroll
        for (int i = 0; i < 8; ++i) { loc[i] = w[t * 8 + i]; s += loc[i]; }
        part[t] = s;
        __syncthreads();
        if (t == 0) {
            float a = 0.f;
            for (int i = 0; i < 256; ++i) { float tmp = part[i]; part[i] = a; a += tmp; }
        }
        __syncthreads();
        float a = part[t];
        #pragma unroll
        for (int i = 0; i < 8; ++i) { a += loc[i]; S[t * 8 + i] = a; }
        __syncthreads();
        const float w0 = S[0];
        #pragma unroll
        for (int i = 0; i < 8; ++i) {
            int j = t * 8 + i;
            z[j] = S[j] + S[2047 - j] - w0;
        }
    }
}

// ---- vt: chunk[((n*NT+kk)*1024 + c)*8 + h] (16B) =
//      bf16(v[n][kk*64 + h*8 + j][c]), j=0..7 ----
__global__ __launch_bounds__(256) void pb_vtile(const float* __restrict__ v,
                                                s16x8* __restrict__ vt) {
    __shared__ __align__(16) short Ts[256 * 64];   // 32 KB
    const int kk = blockIdx.x, cg4 = blockIdx.y, n = blockIdx.z;
    const int l0 = kk * 64, c0 = cg4 * 256;
    const int t = threadIdx.x;
    const float* vn = v + (size_t)n * L * HD;

    #pragma unroll
    for (int i = 0; i < 16; ++i) {
        int unit = i * 256 + t;
        int l = unit >> 6, cq = unit & 63;
        fl4 x = *(const fl4*)&vn[(size_t)(l0 + l) * HD + c0 + cq * 4];
        int lsub = l & 7, lblk = l >> 3;
        #pragma unroll
        for (int j = 0; j < 4; ++j) {
            int c = cq * 4 + j;
            Ts[c * 64 + ((lblk ^ ((c >> 2) & 7)) << 3) + lsub] = f2bf(x[j]);
        }
    }
    __syncthreads();

    s16x8* outp = vt + ((size_t)(n * NT + kk) * 1024 + c0) * 8;
    #pragma unroll
    for (int i2 = 0; i2 < 8; ++i2) {
        int ci = i2 * 256 + t;
        int c = ci >> 3, h = ci & 7;
        int slot = h ^ ((c >> 2) & 7);
        outp[ci] = *(const s16x8*)&Ts[c * 64 + slot * 8];
    }
}

// ---- main GEMM: 128x128 tile, BK=64, 4 waves, 2 blocks/CU, 2 jm-strips.
//      B: LDS dbuf (gload_lds, r6-validated). A: Toeplitz register ring
//      fed by inline-asm global_load_dwordx4 from p8 (4 new frags/tile). ----
__global__ __launch_bounds__(256, 2) void pb_gemm(const short* __restrict__ p8,
                                                  const short* __restrict__ vt,
                                                  float* __restrict__ out) {
    __shared__ __align__(16) short lds_[16384];  // 32 KB: 2 x 16 KB B buffers

    const int bid = blockIdx.x;          // 512 blocks
    const int cm  = bid & 7;             // XCD = cm
    const int n   = (bid >> 3) & 7;
    const int jmq = bid >> 6;            // 0..7; strips jm = jmq, jmq+8
    const int c0 = cm * 128;

    const int t = threadIdx.x;
    const int lane = t & 63;
    const int w = t >> 6;
    const int wr = w >> 1, wc = w & 1;
    const int fr = lane & 15, fk = lane >> 4;

    // B fragment byte-offsets within a 16 KB buffer (ki=1 via ^64)
    int offB[4];
    #pragma unroll
    for (int nf = 0; nf < 4; ++nf) {
        int c = wc * 64 + nf * 16 + fr;
        offB[nf] = c * 128 + ((fk ^ (c & 7)) << 4);
    }

    // B staging sources (r6-validated): chunk dc = w*256 + i*64 + lane
    const short *b0, *b1, *b2, *b3;
    {
        const size_t bbase = ((size_t)(n * NT) * 1024 + c0) * 8ull;
        int dc, c, h;
        dc = w * 256 + 0 * 64 + lane; c = dc >> 3; h = (dc & 7) ^ (c & 7);
        b0 = vt + (bbase + (size_t)c * 8 + h) * 8;
        dc = w * 256 + 1 * 64 + lane; c = dc >> 3; h = (dc & 7) ^ (c & 7);
        b1 = vt + (bbase + (size_t)c * 8 + h) * 8;
        dc = w * 256 + 2 * 64 + lane; c = dc >> 3; h = (dc & 7) ^ (c & 7);
        b2 = vt + (bbase + (size_t)c * 8 + h) * 8;
        dc = w * 256 + 3 * 64 + lane; c = dc >> 3; h = (dc & 7) ^ (c & 7);
        b3 = vt + (bbase + (size_t)c * 8 + h) * 8;
    }
    const int wB = w * 4096;

#define STAGE_B(par) { \
    char* _d = (char*)lds_ + (par) * 16384 + wB; \
    gload_lds16(srcB0, _d); \
    gload_lds16(srcB1, _d + 1024); \
    gload_lds16(srcB2, _d + 2048); \
    gload_lds16(srcB3, _d + 3072); \
    srcB0 += 65536; srcB1 += 65536; srcB2 += 65536; srcB3 += 65536; }

#define BREAD(par) { \
    const char* _b = (const char*)lds_ + (par) * 16384; \
    _Pragma("unroll") \
    for (int nf = 0; nf < 4; ++nf) { \
        bF[nf][0] = *(const s16x8*)(_b + offB[nf]); \
        bF[nf][1] = *(const s16x8*)(_b + (offB[nf] ^ 64)); } }

// inline-asm A loads: unmovable, unscalarizable; retired by the barrier drain
#define AGLOAD4(D0, D1, D2, D3, PTR) { \
    const short* _p = (PTR); \
    asm volatile("global_load_dwordx4 %0, %1, off"           : "=&v"(D0) : "v"(_p) : "memory"); \
    asm volatile("global_load_dwordx4 %0, %1, off offset:32" : "=&v"(D1) : "v"(_p) : "memory"); \
    asm volatile("global_load_dwordx4 %0, %1, off offset:64" : "=&v"(D2) : "v"(_p) : "memory"); \
    asm volatile("global_load_dwordx4 %0, %1, off offset:96" : "=&v"(D3) : "v"(_p) : "memory"); }

#define AGLOAD2(D0, D1, PTR) { \
    const short* _p = (PTR); \
    asm volatile("global_load_dwordx4 %0, %1, off"           : "=&v"(D0) : "v"(_p) : "memory"); \
    asm volatile("global_load_dwordx4 %0, %1, off offset:32" : "=&v"(D1) : "v"(_p) : "memory"); }

#define MFMA1(a, b, c) __builtin_amdgcn_mfma_f32_16x16x32_bf16(a, b, c, 0, 0, 0)

// args: A(m=0,ki=0),A(0,1),A(1,0),A(1,1),A(2,0),A(2,1),A(3,0),A(3,1)
#define MFMA_8(A00, A01, A10, A11, A20, A21, A30, A31) { \
    __builtin_amdgcn_s_setprio(1); \
    _Pragma("unroll") \
    for (int nf = 0; nf < 4; ++nf) { \
        acc[0][nf] = MFMA1(A00, bF[nf][0], acc[0][nf]); \
        acc[0][nf] = MFMA1(A01, bF[nf][1], acc[0][nf]); \
        acc[1][nf] = MFMA1(A10, bF[nf][0], acc[1][nf]); \
        acc[1][nf] = MFMA1(A11, bF[nf][1], acc[1][nf]); \
        acc[2][nf] = MFMA1(A20, bF[nf][0], acc[2][nf]); \
        acc[2][nf] = MFMA1(A21, bF[nf][1], acc[2][nf]); \
        acc[3][nf] = MFMA1(A30, bF[nf][0], acc[3][nf]); \
        acc[3][nf] = MFMA1(A31, bF[nf][1], acc[3][nf]); } \
    __builtin_amdgcn_s_setprio(0); }

    for (int strip = 0; strip < 2; ++strip) {
        const int j0 = jmq * 128 + strip * 1024;

        // A ring base: per-lane 16B-aligned pointer at p-offset u (delta=0)
        // u = 2047 - j0 - wr*64 + fk*8 - fr ; srow = u&7 invariant in T
        const short* ag;
        {
            int u = 2047 - j0 - wr * 64 + fk * 8 - fr;
            ag = p8 + (u & 7) * PROW + (u & ~7);
        }

        // reset B sources for this strip (B panel identical across strips)
        const short* srcB0 = b0; const short* srcB1 = b1;
        const short* srcB2 = b2; const short* srcB3 = b3;

        f32x4 acc[4][4] = {};
        s16x8 X0, X1, X2, X3, Y0, Y1, Y2, Y3, bF[4][2];

        // ---- prologue: stage B(0); ring slots for tile 0 ----
        STAGE_B(0);
        AGLOAD4(X0, X1, X2, X3, ag - 16);   // delta -16, 0, 16, 32
        AGLOAD2(Y2, Y3, ag - 48);           // delta -48, -32
        __syncthreads();                    // drains everything

        for (int T = 0; T < 32; T += 2) {
            // ---- even body: tile T, reads buf0 ----
            STAGE_B(1);                     // B(T+1)
            BREAD(0);
            MFMA_8(X1, X3, X0, X2, Y3, X1, Y2, X0);
            AGLOAD4(Y0, Y1, Y2, Y3, ag + T * 64 + 48);   // for tile T+1
            __syncthreads();

            // ---- odd body: tile T+1, reads buf1 ----
            if (T < 30) { STAGE_B(0); }     // B(T+2)
            BREAD(1);
            MFMA_8(Y1, Y3, Y0, Y2, X3, Y1, X2, Y0);
            if (T < 30) { AGLOAD4(X0, X1, X2, X3, ag + T * 64 + 112); }
            __syncthreads();
        }

        // ---- epilogue: C/D layout col=lane&15, row=(lane>>4)*4+r ----
        float* outn = out + (size_t)n * L * HD;
        #pragma unroll
        for (int m = 0; m < 4; ++m) {
            const int row = j0 + wr * 64 + m * 16 + fk * 4;
            #pragma unroll
            for (int nf = 0; nf < 4; ++nf) {
                const int col = c0 + wc * 64 + nf * 16 + fr;
                #pragma unroll
                for (int r = 0; r < 4; ++r)
                    outn[(size_t)(row + r) * HD + col] = acc[m][nf][r];
            }
        }
    }
}

extern "C" void kernel_launch(void* const* d_in, const int* in_sizes, int n_in,
                              void* d_out, int out_size, void* d_ws, size_t ws_size,
                              hipStream_t stream) {
    const float* v = (const float*)d_in[0];
    const float* w = (const float*)d_in[1];
    float* out = (float*)d_out;

    short* p8 = (short*)d_ws;                          // 64 KB
    s16x8* vt = (s16x8*)((char*)d_ws + 65536);         // 32 MB

    pb_prep<<<129, 256, 0, stream>>>(w, p8, out + (size_t)NB * L * HD);
    pb_vtile<<<dim3(NT, 4, NB), 256, 0, stream>>>(v, vt);
    pb_gemm<<<512, 256, 0, stream>>>(p8, (const short*)vt, out);
}